// Round 5
// baseline (407.760 us; speedup 1.0000x reference)
//
#include <hip/hip_runtime.h>
#include <hip/hip_bf16.h>
#include <math.h>

constexpr int B = 2, L = 1024, D = 1024, H = 16, DK = 64;
constexpr int M = B * L;           // 2048 rows
constexpr int DD = D * D;

typedef __attribute__((ext_vector_type(8))) short bf16x8;
typedef __attribute__((ext_vector_type(4))) float f32x4;

#define SB0() __builtin_amdgcn_sched_barrier(0)

__device__ inline unsigned short f2bf(float f) {
    __hip_bfloat16 h = __float2bfloat16(f);
    return __builtin_bit_cast(unsigned short, h);
}

// async global->LDS, 16B per lane; LDS dest = base + lane*16 (wave-uniform base)
__device__ inline void glds16(const void* g, void* l) {
    __builtin_amdgcn_global_load_lds((const __attribute__((address_space(1))) void*)g,
                                     (__attribute__((address_space(3))) void*)l,
                                     16, 0, 0);
}

// ---------------- LayerNorm + lsm: qn16 = LN(query), q16 = bf16(query) ------
__global__ __launch_bounds__(256) void ln2_kernel(const float* __restrict__ x,
                                                  const float* __restrict__ gamma,
                                                  const float* __restrict__ beta,
                                                  const float* __restrict__ lex,
                                                  const int* __restrict__ mask,
                                                  unsigned short* __restrict__ qn16,
                                                  unsigned short* __restrict__ q16,
                                                  float* __restrict__ lsmout) {
    int row = blockIdx.x;
    int t = threadIdx.x;
    if (t == 0) lsmout[row] = mask[row] ? lex[row] : -1e30f;
    const float4 v = ((const float4*)(x + (size_t)row * D))[t];
    float s  = v.x + v.y + v.z + v.w;
    float sq = v.x*v.x + v.y*v.y + v.z*v.z + v.w*v.w;
    #pragma unroll
    for (int m = 32; m >= 1; m >>= 1) {
        s  += __shfl_xor(s, m, 64);
        sq += __shfl_xor(sq, m, 64);
    }
    __shared__ float rs[4], rq[4];
    int wid = t >> 6;
    if ((t & 63) == 0) { rs[wid] = s; rq[wid] = sq; }
    __syncthreads();
    s  = rs[0] + rs[1] + rs[2] + rs[3];
    sq = rq[0] + rq[1] + rq[2] + rq[3];
    float mean = s * (1.0f / D);
    float var  = sq * (1.0f / D) - mean * mean;
    float rstd = rsqrtf(var + 1e-6f);
    float4 g  = ((const float4*)gamma)[t];
    float4 bb = ((const float4*)beta)[t];
    ushort4 on, oq;
    on.x = f2bf((v.x - mean) * rstd * g.x + bb.x);
    on.y = f2bf((v.y - mean) * rstd * g.y + bb.y);
    on.z = f2bf((v.z - mean) * rstd * g.z + bb.z);
    on.w = f2bf((v.w - mean) * rstd * g.w + bb.w);
    oq.x = f2bf(v.x); oq.y = f2bf(v.y); oq.z = f2bf(v.z); oq.w = f2bf(v.w);
    ((ushort4*)(qn16 + (size_t)row * D))[t] = on;
    ((ushort4*)(q16  + (size_t)row * D))[t] = oq;
}

// ---------------- weight cast: 4 x (D,D) fp32 -> bf16 ----------------------
__global__ __launch_bounds__(256) void wconv_kernel(const float* __restrict__ Wq,
                                                    const float* __restrict__ Wk,
                                                    const float* __restrict__ Wv,
                                                    const float* __restrict__ Wo,
                                                    unsigned short* __restrict__ out) {
    const float* src = (blockIdx.y == 0) ? Wq : (blockIdx.y == 1) ? Wk
                       : (blockIdx.y == 2) ? Wv : Wo;
    size_t i = (size_t)blockIdx.x * 256 + threadIdx.x;
    float4 v = ((const float4*)src)[i];
    ushort4 o;
    o.x = f2bf(v.x); o.y = f2bf(v.y); o.z = f2bf(v.z); o.w = f2bf(v.w);
    ((ushort4*)(out + (size_t)blockIdx.y * DD))[i] = o;
}

// ---------------- fused QKV GEMM: 128x128, BK=64, dbuf + counted vmcnt ------
__global__ __launch_bounds__(256) void gemm_qkv(
        const unsigned short* __restrict__ qn16, const unsigned short* __restrict__ q16,
        const unsigned short* __restrict__ W,
        const float* __restrict__ bq, const float* __restrict__ bk,
        const float* __restrict__ bv,
        unsigned short* __restrict__ Qm, unsigned short* __restrict__ Km,
        unsigned short* __restrict__ Vm) {
    __shared__ __align__(16) unsigned short As[2][8192];
    __shared__ __align__(16) unsigned short Ws[2][8192];
    int t = threadIdx.x, lane = t & 63, w = t >> 6;
    int quad = lane >> 4, l15 = lane & 15;
    int nt = blockIdx.x;                 // 0..23
    int bm = blockIdx.y * 128;
    const unsigned short* A = (nt < 8) ? qn16 : q16;
    const float* bias = (nt < 8) ? bq : ((nt < 16) ? bk : bv);
    unsigned short* Cout = (nt < 8) ? Qm : ((nt < 16) ? Km : Vm);
    int bn_local = (nt & 7) * 128;
    int wm = (w >> 1) * 64, wn = (w & 1) * 64;
    const unsigned short* ap0 = A + (size_t)(bm + w * 32) * D;
    const unsigned short* wp0 = W + (size_t)(nt * 128 + w * 32) * D;
    f32x4 acc[4][4] = {};

    // stage kt -> buf c (8 glds/wave)
    #define QKV_STAGE(kt, c)                                                  \
        {                                                                     \
            const unsigned short* ap = ap0 + (kt) * 64;                       \
            const unsigned short* wp = wp0 + (kt) * 64;                       \
            _Pragma("unroll")                                                 \
            for (int i = 0; i < 4; i++) {                                     \
                int cc = i * 64 + lane;                                       \
                int r = cc >> 3, g = (cc & 7) ^ (r & 7);                      \
                glds16(ap + (size_t)r * D + g * 8, &As[c][w * 2048 + i * 512]);\
                glds16(wp + (size_t)r * D + g * 8, &Ws[c][w * 2048 + i * 512]);\
            }                                                                 \
        }

    SB0();
    QKV_STAGE(0, 0);
    SB0();
    for (int kt = 0; kt < 16; kt++) {
        int c = kt & 1;
        if (kt < 15) {
            SB0();
            QKV_STAGE(kt + 1, c ^ 1);
            SB0();
            asm volatile("s_waitcnt vmcnt(8)" ::: "memory");
        } else {
            SB0();
            asm volatile("s_waitcnt vmcnt(0)" ::: "memory");
        }
        SB0();
        __builtin_amdgcn_s_barrier();      // all waves' stage-kt landed
        SB0();
        #pragma unroll
        for (int k2 = 0; k2 < 2; k2++) {
            bf16x8 av[4], bw[4];
            #pragma unroll
            for (int i = 0; i < 4; i++) {
                int r = wm + i * 16 + l15;
                av[i] = *(const bf16x8*)&As[c][r * 64 + (((quad + 4 * k2) ^ (r & 7)) * 8)];
            }
            #pragma unroll
            for (int j = 0; j < 4; j++) {
                int r = wn + j * 16 + l15;
                bw[j] = *(const bf16x8*)&Ws[c][r * 64 + (((quad + 4 * k2) ^ (r & 7)) * 8)];
            }
            #pragma unroll
            for (int i = 0; i < 4; i++)
                #pragma unroll
                for (int j = 0; j < 4; j++)
                    acc[i][j] = __builtin_amdgcn_mfma_f32_16x16x32_bf16(av[i], bw[j], acc[i][j], 0, 0, 0);
        }
        SB0();
        __builtin_amdgcn_s_barrier();      // reads done before next overwrite
        SB0();
    }
    #pragma unroll
    for (int j = 0; j < 4; j++) {
        int col = bn_local + wn + j * 16 + l15;
        float bcol = bias[col];
        #pragma unroll
        for (int i = 0; i < 4; i++)
            #pragma unroll
            for (int rg = 0; rg < 4; rg++) {
                int row = bm + wm + i * 16 + quad * 4 + rg;
                Cout[(size_t)row * D + col] = f2bf(acc[i][j][rg] + bcol);
            }
    }
    #undef QKV_STAGE
}

// ---------------- V transpose: Vm [b,s,h*64+d] -> Vt [bh][d][s] ------------
__global__ __launch_bounds__(256) void vtrans_kernel(const unsigned short* __restrict__ Vm,
                                                     unsigned short* __restrict__ Vt) {
    __shared__ unsigned short sb[128 * 66];
    int t = threadIdx.x;
    int z = blockIdx.y;
    int b = z >> 4, h = z & 15;
    int s0 = blockIdx.x * 128;
    size_t base = (size_t)b * L * D + (size_t)h * 64;
    #pragma unroll
    for (int i = 0; i < 4; i++) {
        int idx = t + 256 * i;
        int r = idx >> 3, c8 = idx & 7;
        uint4 vv = *(const uint4*)&Vm[base + (size_t)(s0 + r) * D + c8 * 8];
        unsigned int* sp = (unsigned int*)&sb[r * 66 + c8 * 8];
        sp[0] = vv.x; sp[1] = vv.y; sp[2] = vv.z; sp[3] = vv.w;
    }
    __syncthreads();
    #pragma unroll
    for (int i = 0; i < 4; i++) {
        int idx = t + 256 * i;
        int d = idx >> 4, sc = idx & 15;
        unsigned short tmp[8];
        #pragma unroll
        for (int j = 0; j < 8; j++) tmp[j] = sb[(sc * 8 + j) * 66 + d];
        *(uint4*)&Vt[((size_t)z * 64 + d) * L + s0 + sc * 8] = *(uint4*)tmp;
    }
}

// ---------------- fused attention + PV: 4-wave blocks, 4 blocks/CU ----------
// Wave w owns s-quarter [w*256, +256): 8 stages of 32 s-rows.
// Phase 1: ZERO barriers (K staging wave-private in LDS dbuf, vmcnt(8)
// counted; bias pos/postag double-buffered in registers; lsm from LDS).
// Phase 2: wave-private V dbuf (vmcnt(4)); p_sh cross-wave with 2 raw
// s_barriers per stage (no vmcnt drain -- V prefetch crosses barriers).
__global__ __launch_bounds__(256, 4) void attn_pv_kernel(
        const unsigned short* __restrict__ Qm, const unsigned short* __restrict__ Km,
        const unsigned short* __restrict__ Vt,
        const float* __restrict__ pos_bias, const float* __restrict__ postag,
        const float* __restrict__ lsm, float* __restrict__ attn_out,
        unsigned short* __restrict__ ctx16) {
    // pool: wave-private K/V dbuf: buf c at c*8192 + w*2048 (2048 shorts/wave)
    __shared__ __align__(16) unsigned short pool[16384];      // 32 KB
    // reg2 overlay: phase1 {lsm_sh[1024]f32 | q_sh[16][72] | redA | redB}
    //               phase2 {p_sh[16][136]}
    __shared__ __align__(16) unsigned short reg2[3456];       // 6.9 KB
    float* lsm_sh = (float*)reg2;
    unsigned short (*q_sh)[72] = (unsigned short(*)[72])(reg2 + 2048);
    float (*redA)[4] = (float(*)[4])(reg2 + 3200);
    float (*redB)[4] = (float(*)[4])(reg2 + 3328);
    unsigned short (*p_sh)[136] = (unsigned short(*)[136])reg2;

    int t = threadIdx.x, lane = t & 63, w = t >> 6;           // w in 0..3
    int quad = lane >> 4, l15 = lane & 15;
    int qt = blockIdx.x & 63;
    int bh = blockIdx.x >> 6;
    int b = bh >> 4, h = bh & 15;
    int q0 = qt * 16;
    int q = q0 + l15;
    size_t base = (size_t)b * L * D + (size_t)h * DK;

    if (t < 128) {
        int r = t >> 3, c8 = t & 7;
        *(uint4*)&q_sh[r][c8 * 8] = *(const uint4*)&Qm[base + (size_t)(q0 + r) * D + c8 * 8];
    }
    ((float4*)lsm_sh)[t] = ((const float4*)(lsm + b * L))[t];
    __syncthreads();                       // drains; vmcnt baseline = 0
    bf16x8 qb0 = *(const bf16x8*)&q_sh[l15][quad * 8];
    bf16x8 qb1 = *(const bf16x8*)&q_sh[l15][32 + quad * 8];

    const float* pbp = pos_bias + ((size_t)h * L + q) * L;
    const float* ptp = postag + ((size_t)bh * L + q) * L;
    const unsigned short* kbase = Km + base + (size_t)(w * 256) * D;
    int squad = w * 256 + quad * 4;        // this lane's base s

    // ---- Phase 1 prologue: K(0) glds + bias(0) regs -----------------------
    SB0();
    #pragma unroll
    for (int i = 0; i < 4; i++) {
        int r = i * 8 + (lane >> 3);
        int g = (lane & 7) ^ (r & 7);
        glds16(kbase + (size_t)r * D + g * 8, &pool[w * 2048 + i * 512]);
    }
    SB0();
    float4 pbc0 = *(const float4*)(pbp + squad);
    float4 pbc1 = *(const float4*)(pbp + squad + 16);
    float4 ptc0 = *(const float4*)(ptp + squad);
    float4 ptc1 = *(const float4*)(ptp + squad + 16);
    SB0();

    f32x4 acc[16] = {};
    #pragma unroll
    for (int st = 0; st < 8; st++) {
        int bc = st & 1;
        float4 pbn0, pbn1, ptn0, ptn1;
        if (st < 7) {
            SB0();
            const unsigned short* kpn = kbase + (size_t)((st + 1) * 32) * D;
            #pragma unroll
            for (int i = 0; i < 4; i++) {
                int r = i * 8 + (lane >> 3);
                int g = (lane & 7) ^ (r & 7);
                glds16(kpn + (size_t)r * D + g * 8,
                       &pool[(bc ^ 1) * 8192 + w * 2048 + i * 512]);
            }
            SB0();
            int sn = squad + (st + 1) * 32;
            pbn0 = *(const float4*)(pbp + sn);
            pbn1 = *(const float4*)(pbp + sn + 16);
            ptn0 = *(const float4*)(ptp + sn);
            ptn1 = *(const float4*)(ptp + sn + 16);
            SB0();
            asm volatile("s_waitcnt vmcnt(8)" ::: "memory");   // stage st landed
        } else {
            SB0();
            asm volatile("s_waitcnt vmcnt(0)" ::: "memory");
        }
        SB0();
        int r7 = l15 & 7;
        const unsigned short* kB = &pool[bc * 8192 + w * 2048];
        bf16x8 ka00 = *(const bf16x8*)&kB[l15 * 64 + ((quad ^ r7) * 8)];
        bf16x8 ka01 = *(const bf16x8*)&kB[l15 * 64 + (((quad + 4) ^ r7) * 8)];
        bf16x8 ka10 = *(const bf16x8*)&kB[(16 + l15) * 64 + ((quad ^ r7) * 8)];
        bf16x8 ka11 = *(const bf16x8*)&kB[(16 + l15) * 64 + (((quad + 4) ^ r7) * 8)];
        float4 l0 = *(const float4*)&lsm_sh[squad + st * 32];
        float4 l1 = *(const float4*)&lsm_sh[squad + st * 32 + 16];
        int ti0 = 2 * st, ti1 = ti0 + 1;
        acc[ti0] = __builtin_amdgcn_mfma_f32_16x16x32_bf16(ka00, qb0, acc[ti0], 0, 0, 0);
        acc[ti0] = __builtin_amdgcn_mfma_f32_16x16x32_bf16(ka01, qb1, acc[ti0], 0, 0, 0);
        acc[ti1] = __builtin_amdgcn_mfma_f32_16x16x32_bf16(ka10, qb0, acc[ti1], 0, 0, 0);
        acc[ti1] = __builtin_amdgcn_mfma_f32_16x16x32_bf16(ka11, qb1, acc[ti1], 0, 0, 0);
        acc[ti0][0] = acc[ti0][0] * 0.125f + (pbc0.x + ptc0.x + l0.x);
        acc[ti0][1] = acc[ti0][1] * 0.125f + (pbc0.y + ptc0.y + l0.y);
        acc[ti0][2] = acc[ti0][2] * 0.125f + (pbc0.z + ptc0.z + l0.z);
        acc[ti0][3] = acc[ti0][3] * 0.125f + (pbc0.w + ptc0.w + l0.w);
        acc[ti1][0] = acc[ti1][0] * 0.125f + (pbc1.x + ptc1.x + l1.x);
        acc[ti1][1] = acc[ti1][1] * 0.125f + (pbc1.y + ptc1.y + l1.y);
        acc[ti1][2] = acc[ti1][2] * 0.125f + (pbc1.z + ptc1.z + l1.z);
        acc[ti1][3] = acc[ti1][3] * 0.125f + (pbc1.w + ptc1.w + l1.w);
        if (st < 7) { pbc0 = pbn0; pbc1 = pbn1; ptc0 = ptn0; ptc1 = ptn1; }
    }
    // ---- softmax over s: per-lane -> quads (shfl 16,32) -> 4 waves (LDS) --
    float mx = -1e30f;
    #pragma unroll
    for (int ti = 0; ti < 16; ti++)
        #pragma unroll
        for (int rg = 0; rg < 4; rg++) mx = fmaxf(mx, acc[ti][rg]);
    mx = fmaxf(mx, __shfl_xor(mx, 16, 64));
    mx = fmaxf(mx, __shfl_xor(mx, 32, 64));
    if (quad == 0) redA[l15][w] = mx;
    __syncthreads();
    mx = fmaxf(fmaxf(redA[l15][0], redA[l15][1]), fmaxf(redA[l15][2], redA[l15][3]));
    float sum = 0.f;
    #pragma unroll
    for (int ti = 0; ti < 16; ti++)
        #pragma unroll
        for (int rg = 0; rg < 4; rg++) {
            float e = __expf(acc[ti][rg] - mx);
            acc[ti][rg] = e;
            sum += e;
        }
    sum += __shfl_xor(sum, 16, 64);
    sum += __shfl_xor(sum, 32, 64);
    if (quad == 0) redB[l15][w] = sum;
    __syncthreads();
    float inv = 1.0f / (redB[l15][0] + redB[l15][1] + redB[l15][2] + redB[l15][3]);
    // ---- write attn (float4 along s); keep normalized P in acc ------------
    #pragma unroll
    for (int ti = 0; ti < 16; ti++) {
        int s0 = w * 256 + (ti >> 1) * 32 + (ti & 1) * 16 + quad * 4;
        float4 o;
        o.x = acc[ti][0] * inv; o.y = acc[ti][1] * inv;
        o.z = acc[ti][2] * inv; o.w = acc[ti][3] * inv;
        acc[ti][0] = o.x; acc[ti][1] = o.y; acc[ti][2] = o.z; acc[ti][3] = o.w;
        *(float4*)&attn_out[((size_t)bh * L + q) * L + s0] = o;
    }
    __syncthreads();                       // q_sh/lsm/red dead; p_sh overlay safe
    // ---- Phase 2: ctx = P V; wave w owns d-rows [w*16,+16) ----------------
    f32x4 cacc = {};
    const unsigned short* vbase = Vt + ((size_t)bh * 64 + w * 16) * L;
    SB0();
    #pragma unroll
    for (int i = 0; i < 4; i++) {          // V stage 0 -> buf 0
        int r = i * 4 + (lane >> 4);
        int g = (lane & 15) ^ (r & 7);
        glds16(vbase + (size_t)r * L + g * 8, &pool[w * 2048 + i * 512]);
    }
    SB0();
    #pragma unroll
    for (int st = 0; st < 8; st++) {
        int bc = st & 1;
        if (st < 7) {
            SB0();
            #pragma unroll
            for (int i = 0; i < 4; i++) {
                int r = i * 4 + (lane >> 4);
                int g = (lane & 15) ^ (r & 7);
                glds16(vbase + (size_t)r * L + (st + 1) * 128 + g * 8,
                       &pool[(bc ^ 1) * 8192 + w * 2048 + i * 512]);
            }
            SB0();
        }
        // fill p_sh(st): filler wave = st>>1, tiles (st&1)*8 + u
        if (w == (st >> 1)) {
            #pragma unroll
            for (int u = 0; u < 8; u++) {
                f32x4 p = acc[(st & 1) * 8 + u];
                ushort4 pu;
                pu.x = f2bf(p[0]); pu.y = f2bf(p[1]); pu.z = f2bf(p[2]); pu.w = f2bf(p[3]);
                *(ushort4*)&p_sh[l15][u * 16 + quad * 4] = pu;
            }
        }
        asm volatile("s_waitcnt lgkmcnt(0)" ::: "memory");     // p writes in LDS
        SB0();
        if (st < 7) asm volatile("s_waitcnt vmcnt(4)" ::: "memory");  // V st landed
        else        asm volatile("s_waitcnt vmcnt(0)" ::: "memory");
        SB0();
        __builtin_amdgcn_s_barrier();      // p_sh(st) visible to all waves
        SB0();
        const unsigned short* vB = &pool[bc * 8192 + w * 2048];
        #pragma unroll
        for (int kk = 0; kk < 4; kk++) {
            bf16x8 vf = *(const bf16x8*)&vB[l15 * 128 + (((kk * 4 + quad) ^ (l15 & 7)) * 8)];
            bf16x8 pf = *(const bf16x8*)&p_sh[l15][kk * 32 + quad * 8];
            cacc = __builtin_amdgcn_mfma_f32_16x16x32_bf16(pf, vf, cacc, 0, 0, 0);
        }
        SB0();
        __builtin_amdgcn_s_barrier();      // reads done before next p fill
        SB0();
    }
    // ctx[d = w*16+l15][q = quad*4+rg] -> ctx16[(b*L + q0 + q)*D + h*64 + d]
    size_t cbase = ((size_t)b * L + q0) * D + (size_t)h * 64 + w * 16 + l15;
    #pragma unroll
    for (int rg = 0; rg < 4; rg++)
        ctx16[cbase + (size_t)(quad * 4 + rg) * D] = f2bf(cacc[rg]);
}

// ---------------- out GEMM: 64x64 tile, dbuf + counted vmcnt ---------------
__global__ __launch_bounds__(256) void gemm_out(
        const unsigned short* __restrict__ A, const unsigned short* __restrict__ W,
        const float* __restrict__ bias, const float* __restrict__ res,
        float* __restrict__ C) {
    __shared__ __align__(16) unsigned short As[2][4096];
    __shared__ __align__(16) unsigned short Ws[2][4096];
    int t = threadIdx.x, lane = t & 63, w = t >> 6;
    int quad = lane >> 4, l15 = lane & 15;
    int bm = blockIdx.x * 64, bn = blockIdx.y * 64;
    int wm = (w >> 1) * 32, wn = (w & 1) * 32;
    const unsigned short* ap0 = A + (size_t)(bm + w * 16) * D;
    const unsigned short* wp0 = W + (size_t)(bn + w * 16) * D;
    f32x4 acc[2][2] = {};

    #define OUT_STAGE(kt, c)                                                  \
        {                                                                     \
            const unsigned short* ap = ap0 + (kt) * 64;                       \
            const unsigned short* wp = wp0 + (kt) * 64;                       \
            _Pragma("unroll")                                                 \
            for (int i = 0; i < 2; i++) {                                     \
                int cc = i * 64 + lane;                                       \
                int r = cc >> 3, g = (cc & 7) ^ (r & 7);                      \
                glds16(ap + (size_t)r * D + g * 8, &As[c][w * 1024 + i * 512]);\
                glds16(wp + (size_t)r * D + g * 8, &Ws[c][w * 1024 + i * 512]);\
            }                                                                 \
        }

    SB0();
    OUT_STAGE(0, 0);
    SB0();
    for (int kt = 0; kt < 16; kt++) {
        int c = kt & 1;
        if (kt < 15) {
            SB0();
            OUT_STAGE(kt + 1, c ^ 1);
            SB0();
            asm volatile("s_waitcnt vmcnt(4)" ::: "memory");
        } else {
            SB0();
            asm volatile("s_waitcnt vmcnt(0)" ::: "memory");
        }
        SB0();
        __builtin_amdgcn_s_barrier();
        SB0();
        #pragma unroll
        for (int k2 = 0; k2 < 2; k2++) {
            bf16x8 av[2], bw[2];
            #pragma unroll
            for (int i = 0; i < 2; i++) {
                int r = wm + i * 16 + l15;
                av[i] = *(const bf16x8*)&As[c][r * 64 + (((quad + 4 * k2) ^ (r & 7)) * 8)];
            }
            #pragma unroll
            for (int j = 0; j < 2; j++) {
                int r = wn + j * 16 + l15;
                bw[j] = *(const bf16x8*)&Ws[c][r * 64 + (((quad + 4 * k2) ^ (r & 7)) * 8)];
            }
            #pragma unroll
            for (int i = 0; i < 2; i++)
                #pragma unroll
                for (int j = 0; j < 2; j++)
                    acc[i][j] = __builtin_amdgcn_mfma_f32_16x16x32_bf16(av[i], bw[j], acc[i][j], 0, 0, 0);
        }
        SB0();
        __builtin_amdgcn_s_barrier();
        SB0();
    }
    #pragma unroll
    for (int j = 0; j < 2; j++) {
        int col = bn + wn + j * 16 + l15;
        float bcol = bias[col];
        #pragma unroll
        for (int i = 0; i < 2; i++)
            #pragma unroll
            for (int rg = 0; rg < 4; rg++) {
                int row = bm + wm + i * 16 + quad * 4 + rg;
                C[(size_t)row * D + col] = acc[i][j][rg] + bcol + res[(size_t)row * D + col];
            }
    }
    #undef OUT_STAGE
}

extern "C" void kernel_launch(void* const* d_in, const int* in_sizes, int n_in,
                              void* d_out, int out_size, void* d_ws, size_t ws_size,
                              hipStream_t stream) {
    (void)in_sizes; (void)n_in; (void)out_size; (void)ws_size;
    const float* query  = (const float*)d_in[0];
    const float* pos_b  = (const float*)d_in[1];
    const float* postag = (const float*)d_in[2];
    const float* lex    = (const float*)d_in[3];
    const int*   mask   = (const int*)d_in[4];
    const float* Wq = (const float*)d_in[5];
    const float* bq = (const float*)d_in[6];
    const float* Wk = (const float*)d_in[7];
    const float* bk = (const float*)d_in[8];
    const float* Wv = (const float*)d_in[9];
    const float* bv = (const float*)d_in[10];
    const float* Wo = (const float*)d_in[11];
    const float* bo = (const float*)d_in[12];
    const float* gamma = (const float*)d_in[13];
    const float* beta  = (const float*)d_in[14];

    float* out  = (float*)d_out;                 // (B,L,D)
    float* attn = out + (size_t)B * L * D;       // (B,H,L,L)

    unsigned short* ws16 = (unsigned short*)d_ws;
    const size_t NE = (size_t)M * D;
    unsigned short* qn16  = ws16;
    unsigned short* q16   = ws16 + NE;
    unsigned short* W16   = ws16 + 2 * NE;       // 4*DD
    unsigned short* Qm16  = W16 + 4 * (size_t)DD;
    unsigned short* Km16  = Qm16 + NE;
    unsigned short* Vm16  = Km16 + NE;
    unsigned short* Vt16  = Vm16 + NE;           // [32][64][1024]
    unsigned short* ctx16 = Vt16 + NE;
    float* lsm = (float*)(ctx16 + NE);           // (B,L) fused lex+mask

    ln2_kernel<<<M, 256, 0, stream>>>(query, gamma, beta, lex, mask, qn16, q16, lsm);
    wconv_kernel<<<dim3(DD / 1024, 4), 256, 0, stream>>>(Wq, Wk, Wv, Wo, W16);
    gemm_qkv<<<dim3(24, 16), 256, 0, stream>>>(qn16, q16, W16, bq, bk, bv,
                                               Qm16, Km16, Vm16);
    vtrans_kernel<<<dim3(8, 32), 256, 0, stream>>>(Vm16, Vt16);
    attn_pv_kernel<<<B * H * (L / 16), 256, 0, stream>>>(Qm16, Km16, Vt16,
                                                         pos_b, postag, lsm,
                                                         attn, ctx16);
    gemm_out<<<dim3(32, 16), 256, 0, stream>>>(ctx16, W16 + 3 * (size_t)DD, bo, query, out);
}